// Round 2
// baseline (789.332 us; speedup 1.0000x reference)
//
#include <hip/hip_runtime.h>
#include <math.h>

#define S_TOK 2048
#define HID   2048
#define FFN_  2048
#define NEXP  8
#define NSLOT (S_TOK*2)

typedef short  s8v __attribute__((ext_vector_type(8)));
typedef short  s4v __attribute__((ext_vector_type(4)));
typedef float  f4v __attribute__((ext_vector_type(4)));

__device__ __forceinline__ unsigned short f32_bf16(float f){
  unsigned u = __float_as_uint(f);
  u += 0x7fffu + ((u>>16)&1u);          // RNE
  return (unsigned short)(u>>16);
}
// swizzled LDS layout: granule (r,kq) lives at position (r*4 + (kq ^ ((r>>2)&3)))
// fragment b128 reads are 2-way (free); staging writes are linear (global_load_lds).
__device__ __forceinline__ int lds_off(int r,int kq){
  return (r*4 + (kq ^ ((r>>2)&3)))*8;
}
// async global->LDS, 16B per lane; LDS dest = wave-uniform base + lane*16
__device__ __forceinline__ void gl_lds16(const unsigned short* g, unsigned short* l){
  __builtin_amdgcn_global_load_lds(
      (const __attribute__((address_space(1))) unsigned int*)(const void*)g,
      (__attribute__((address_space(3))) unsigned int*)(void*)l,
      16, 0, 0);
}

// ---------------- init: zero counts/cursors/offs ----------------
__global__ void init_k(int* hdr){
  if (threadIdx.x < 24) hdr[threadIdx.x] = 0;
}

// ---------------- zero the output (gemm2 accumulates atomically) ----------------
__global__ __launch_bounds__(256) void zero_k(float* __restrict__ p){
  int i = (blockIdx.x*256 + threadIdx.x)*4;
  f4v z = {0.f,0.f,0.f,0.f};
  *reinterpret_cast<f4v*>(p + i) = z;
}

// ---------------- prepass: X fp32 -> bf16 (same layout) ----------------
__global__ __launch_bounds__(256) void convX_k(
    const float* __restrict__ X, unsigned short* __restrict__ Xb)
{
  int i = (blockIdx.x*256 + threadIdx.x)*8;
  f4v a = *reinterpret_cast<const f4v*>(X + i);
  f4v b = *reinterpret_cast<const f4v*>(X + i + 4);
  s8v o;
  o[0]=(short)f32_bf16(a[0]); o[1]=(short)f32_bf16(a[1]);
  o[2]=(short)f32_bf16(a[2]); o[3]=(short)f32_bf16(a[3]);
  o[4]=(short)f32_bf16(b[0]); o[5]=(short)f32_bf16(b[1]);
  o[6]=(short)f32_bf16(b[2]); o[7]=(short)f32_bf16(b[3]);
  *reinterpret_cast<s8v*>(Xb + i) = o;
}

// ---------------- prepass: per-expert [K][N] fp32 -> [N][K] bf16 ----------------
// tile 64k x 128n; register 8-row micro-transpose; all-vector LDS + global IO.
__global__ __launch_bounds__(256) void transp_k(
    const float* __restrict__ src, unsigned short* __restrict__ dst,
    int K, int N)
{
  const int e = blockIdx.z;
  const int k0 = blockIdx.y*64, n0 = blockIdx.x*128;
  src += (size_t)e*K*N + (size_t)k0*N + n0;
  dst += (size_t)e*N*K + (size_t)n0*K + k0;
  __shared__ __align__(16) unsigned short t[128*66];
  const int tid = threadIdx.x;
  const int nb = tid & 31;        // n-chunk of 4 floats
  const int kb = tid >> 5;        // k-granule of 8 rows
  f4v f[8];
  #pragma unroll
  for (int j=0;j<8;j++)
    f[j] = *reinterpret_cast<const f4v*>(src + (size_t)(kb*8+j)*N + nb*4);
  #pragma unroll
  for (int c=0;c<4;c++){
    int n = nb*4 + c;
    s8v v;
    #pragma unroll
    for (int j=0;j<8;j++) v[j] = (short)f32_bf16(f[j][c]);
    *reinterpret_cast<s8v*>(&t[n*66 + ((kb ^ ((n>>5)&3))*8)]) = v;
  }
  __syncthreads();
  #pragma unroll
  for (int p=0;p<4;p++){
    int n = p*32 + (tid>>3);
    int c = tid & 7;
    s8v v = *reinterpret_cast<const s8v*>(&t[n*66 + ((c ^ ((n>>5)&3))*8)]);
    *reinterpret_cast<s8v*>(dst + (size_t)n*K + c*8) = v;
  }
}

// ---------------- router: one wave per token, all fp32 ----------------
__global__ __launch_bounds__(64) void router_k(
    const float* __restrict__ X, const float* __restrict__ Wqkv,
    int* __restrict__ hdr, int* __restrict__ idx, float* __restrict__ scr)
{
  const int s = blockIdx.x, lane = threadIdx.x;
  const float* x = X + (size_t)s*HID;
  f4v xv[8];
  #pragma unroll
  for (int i=0;i<8;i++) xv[i] = *reinterpret_cast<const f4v*>(x + (i*64+lane)*4);
  float dot[24];
  #pragma unroll
  for (int o=0;o<24;o++){
    const float* w = Wqkv + (size_t)o*HID;
    float a = 0.f;
    #pragma unroll
    for (int i=0;i<8;i++){
      f4v wv = *reinterpret_cast<const f4v*>(w + (i*64+lane)*4);
      a += xv[i][0]*wv[0] + xv[i][1]*wv[1] + xv[i][2]*wv[2] + xv[i][3]*wv[3];
    }
    #pragma unroll
    for (int off=32; off; off>>=1) a += __shfl_xor(a, off, 64);
    dot[o] = a;
  }
  if (lane==0){
    float lg[8];
    #pragma unroll
    for (int i=0;i<8;i++){
      float qi = dot[i];
      float mx = -1e30f;
      #pragma unroll
      for (int j=0;j<8;j++) mx = fmaxf(mx, qi*dot[8+j]);
      float se=0.f, lv=0.f;
      #pragma unroll
      for (int j=0;j<8;j++){
        float e = expf(qi*dot[8+j] - mx);
        se += e; lv += e*dot[16+j];
      }
      lg[i] = lv/se;
    }
    int i0=0; float v0=lg[0];
    #pragma unroll
    for (int i=1;i<8;i++) if (lg[i]>v0){v0=lg[i];i0=i;}
    int i1=-1; float v1=-1e30f;
    #pragma unroll
    for (int i=0;i<8;i++) if (i!=i0 && lg[i]>v1){v1=lg[i];i1=i;}
    float a  = expf(v1-v0);
    float s0 = 1.f/(1.f+a);
    idx[s*2]=i0; idx[s*2+1]=i1;
    scr[s*2]=s0; scr[s*2+1]=a*s0;
    atomicAdd(&hdr[i0],1); atomicAdd(&hdr[i1],1);
  }
}

// ---------------- scan: exclusive prefix of 8 counts ----------------
__global__ void scan_k(int* hdr){
  if (threadIdx.x==0){
    int a=0;
    for (int e=0;e<NEXP;e++){ hdr[16+e]=a; a+=hdr[e]; }
  }
}

// ---------------- scatter: assign slots ----------------
__global__ __launch_bounds__(256) void scatter_k(
    const int* __restrict__ idx, const float* __restrict__ scr, int* hdr,
    int* __restrict__ tok_slot, float* __restrict__ scr_slot)
{
  int s = blockIdx.x*256 + threadIdx.x;
  if (s >= S_TOK) return;
  #pragma unroll
  for (int k=0;k<2;k++){
    int e    = idx[s*2+k];
    int pos  = atomicAdd(&hdr[8+e], 1);
    int slot = hdr[16+e] + pos;
    tok_slot[slot] = s;
    scr_slot[slot] = scr[s*2+k];
  }
}

// ---------------- grouped GEMM1: inter = silu(X W1g) * (X W1u) ----------------
// grid (FFN/64, S/128, E), block 256. global_load_lds staging (m97 structure).
__global__ __launch_bounds__(256,3) void gemm1_k(
    const unsigned short* __restrict__ Xb, const unsigned short* __restrict__ W1t,
    const int* __restrict__ hdr, const int* __restrict__ tok_slot,
    unsigned short* __restrict__ inter)
{
  const int e = blockIdx.z, mt = blockIdx.y, nt = blockIdx.x;
  const int cnt = hdr[e];
  const int m0  = mt*128;
  if (m0 >= cnt) return;
  const int off = hdr[16+e];
  const int n0  = nt*64;
  const unsigned short* W1e = W1t + (size_t)e*(2*FFN_)*HID;   // [n' (4096)][k (2048)]

  __shared__ __align__(16) unsigned short sA[128*32];
  __shared__ __align__(16) unsigned short sB[128*32];
  __shared__ int sTok[128];

  const int tid = threadIdx.x;
  if (tid < 128){
    int r = m0 + tid; if (r >= cnt) r = cnt-1;
    sTok[tid] = tok_slot[off + r];
  }
  __syncthreads();

  const int lane = tid & 63, wv = tid >> 6;
  const int wm = wv >> 1, wn = wv & 1;
  const int lm = lane & 15, kq = lane >> 4;
  // staging roles: 16 rows/issue/wave, lane -> (row srow, granule kg)
  const int srow = lane >> 2, kg = lane & 3;
  const int kgs  = kg ^ (srow >> 2);        // pre-swizzled source granule

  const unsigned short* gA0 = Xb + (size_t)sTok[wv*16 + srow]*HID      + kgs*8;
  const unsigned short* gA1 = Xb + (size_t)sTok[64 + wv*16 + srow]*HID + kgs*8;
  const unsigned short* gB0 = W1e + (size_t)(n0 + wv*16 + srow)*HID        + kgs*8; // gate
  const unsigned short* gB1 = W1e + (size_t)(FFN_ + n0 + wv*16 + srow)*HID + kgs*8; // up
  unsigned short* lA0 = sA + (wv*16)*32;
  unsigned short* lA1 = sA + (64 + wv*16)*32;
  unsigned short* lB0 = sB + (wv*16)*32;
  unsigned short* lB1 = sB + (64 + wv*16)*32;

  f4v zero = {0.f,0.f,0.f,0.f};
  f4v acc[2][2][4];
  #pragma unroll
  for (int a=0;a<2;a++)
    #pragma unroll
    for (int b=0;b<2;b++)
      #pragma unroll
      for (int c=0;c<4;c++) acc[a][b][c]=zero;

  for (int k0=0; k0<HID; k0+=32){
    gl_lds16(gA0, lA0); gl_lds16(gA1, lA1);
    gl_lds16(gB0, lB0); gl_lds16(gB1, lB1);
    gA0 += 32; gA1 += 32; gB0 += 32; gB1 += 32;
    __syncthreads();
    s8v af[4], bfr[2][2];
    #pragma unroll
    for (int mf=0;mf<4;mf++)
      af[mf] = *reinterpret_cast<const s8v*>(&sA[lds_off(wm*64+mf*16+lm, kq)]);
    #pragma unroll
    for (int st=0; st<2; st++)
      #pragma unroll
      for (int nf=0;nf<2;nf++)
        bfr[st][nf] = *reinterpret_cast<const s8v*>(&sB[lds_off(st*64+wn*32+nf*16+lm, kq)]);
    #pragma unroll
    for (int st=0; st<2; st++)
      #pragma unroll
      for (int nf=0;nf<2;nf++)
        #pragma unroll
        for (int mf=0;mf<4;mf++)
          acc[st][nf][mf] = __builtin_amdgcn_mfma_f32_16x16x32_bf16(
              af[mf], bfr[st][nf], acc[st][nf][mf], 0,0,0);
    __syncthreads();
  }
  // epilogue: silu(g)*u -> bf16 inter
  const int lq = lane>>4;
  #pragma unroll
  for (int nf=0;nf<2;nf++)
    #pragma unroll
    for (int mf=0;mf<4;mf++){
      f4v g = acc[0][nf][mf], u = acc[1][nf][mf];
      #pragma unroll
      for (int r=0;r<4;r++){
        int row = wm*64 + mf*16 + lq*4 + r;
        if (m0+row < cnt){
          float gv = g[r];
          float val = gv / (1.f + expf(-gv)) * u[r];
          inter[(size_t)(off+m0+row)*FFN_ + n0 + wn*32 + nf*16 + lm] = f32_bf16(val);
        }
      }
    }
}

// ---------------- grouped GEMM2 + combine: out[tok] += score * (inter @ W2) ----------------
// grid (HID/128, S/128, E), block 256. global_load_lds staging; atomic combine.
__global__ __launch_bounds__(256,3) void gemm2_k(
    const unsigned short* __restrict__ inter, const unsigned short* __restrict__ W2t,
    const int* __restrict__ hdr, const int* __restrict__ tok_slot,
    const float* __restrict__ scr_slot, float* __restrict__ out)
{
  const int e = blockIdx.z, mt = blockIdx.y, nt = blockIdx.x;
  const int cnt = hdr[e];
  const int m0  = mt*128;
  if (m0 >= cnt) return;
  const int off = hdr[16+e];
  const int n0  = nt*128;
  const unsigned short* W2e = W2t + (size_t)e*HID*FFN_;      // [n (2048)][k (2048)]

  __shared__ __align__(16) unsigned short sA[128*32];
  __shared__ __align__(16) unsigned short sB[128*32];
  __shared__ int   sTok[128];
  __shared__ float sScr[128];

  const int tid = threadIdx.x;
  if (tid < 128){
    int r = m0 + tid; if (r >= cnt) r = cnt-1;
    sTok[tid] = tok_slot[off + r];
    sScr[tid] = scr_slot[off + r];
  }

  const int lane = tid & 63, wv = tid >> 6;
  const int wm = wv >> 1, wn = wv & 1;
  const int lm = lane & 15, kq = lane >> 4;
  const int srow = lane >> 2, kg = lane & 3;
  const int kgs  = kg ^ (srow >> 2);

  int r0 = m0 + wv*16 + srow;      if (r0 >= cnt) r0 = cnt-1;
  int r1 = m0 + 64 + wv*16 + srow; if (r1 >= cnt) r1 = cnt-1;
  const unsigned short* gA0 = inter + (size_t)(off + r0)*FFN_ + kgs*8;
  const unsigned short* gA1 = inter + (size_t)(off + r1)*FFN_ + kgs*8;
  const unsigned short* gB0 = W2e + (size_t)(n0 + wv*16 + srow)*FFN_      + kgs*8;
  const unsigned short* gB1 = W2e + (size_t)(n0 + 64 + wv*16 + srow)*FFN_ + kgs*8;
  unsigned short* lA0 = sA + (wv*16)*32;
  unsigned short* lA1 = sA + (64 + wv*16)*32;
  unsigned short* lB0 = sB + (wv*16)*32;
  unsigned short* lB1 = sB + (64 + wv*16)*32;

  f4v zero = {0.f,0.f,0.f,0.f};
  f4v acc[4][4];
  #pragma unroll
  for (int a=0;a<4;a++)
    #pragma unroll
    for (int b=0;b<4;b++) acc[a][b]=zero;

  __syncthreads();

  for (int k0=0; k0<FFN_; k0+=32){
    gl_lds16(gA0, lA0); gl_lds16(gA1, lA1);
    gl_lds16(gB0, lB0); gl_lds16(gB1, lB1);
    gA0 += 32; gA1 += 32; gB0 += 32; gB1 += 32;
    __syncthreads();
    s8v af[4], bfr[4];
    #pragma unroll
    for (int mf=0;mf<4;mf++)
      af[mf] = *reinterpret_cast<const s8v*>(&sA[lds_off(wm*64+mf*16+lm, kq)]);
    #pragma unroll
    for (int nf=0;nf<4;nf++)
      bfr[nf] = *reinterpret_cast<const s8v*>(&sB[lds_off(wn*64+nf*16+lm, kq)]);
    #pragma unroll
    for (int nf=0;nf<4;nf++)
      #pragma unroll
      for (int mf=0;mf<4;mf++)
        acc[nf][mf] = __builtin_amdgcn_mfma_f32_16x16x32_bf16(
            af[mf], bfr[nf], acc[nf][mf], 0,0,0);
    __syncthreads();
  }
  const int lq = lane>>4;
  #pragma unroll
  for (int nf=0;nf<4;nf++)
    #pragma unroll
    for (int mf=0;mf<4;mf++)
      #pragma unroll
      for (int r=0;r<4;r++){
        int row = wm*64 + mf*16 + lq*4 + r;
        if (m0+row < cnt)
          atomicAdd(&out[(size_t)sTok[row]*HID + n0 + wn*64 + nf*16 + lm],
                    acc[nf][mf][r]*sScr[row]);
      }
}

extern "C" void kernel_launch(void* const* d_in, const int* in_sizes, int n_in,
                              void* d_out, int out_size, void* d_ws, size_t ws_size,
                              hipStream_t stream)
{
  const float* X    = (const float*)d_in[0];
  const float* Wqkv = (const float*)d_in[1];
  const float* W1   = (const float*)d_in[2];
  const float* W2   = (const float*)d_in[3];
  float* out = (float*)d_out;

  // workspace layout (total ~216.1 MB)
  char* ws = (char*)d_ws;
  int*   hdr      = (int*)ws;                              // counts[8], cursor[8], offs[8]
  int*   idx      = (int*)(ws + 4096);
  float* scr      = (float*)(ws + 4096 + 1*16384);
  int*   tok_slot = (int*)(ws + 4096 + 2*16384);
  float* scr_slot = (float*)(ws + 4096 + 3*16384);
  size_t o = 4096 + 4*16384;                               // 69632
  unsigned short* Xb    = (unsigned short*)(ws + o); o += (size_t)S_TOK*HID*2;       // 8 MB
  unsigned short* inter = (unsigned short*)(ws + o); o += (size_t)NSLOT*FFN_*2;      // 16 MB
  unsigned short* W1t   = (unsigned short*)(ws + o); o += (size_t)NEXP*2*FFN_*HID*2; // 128 MB
  unsigned short* W2t   = (unsigned short*)(ws + o);                                 // 64 MB

  init_k   <<<1,   64, 0, stream>>>(hdr);
  zero_k   <<<(S_TOK*HID/4)/256, 256, 0, stream>>>(out);
  convX_k  <<<(S_TOK*HID/8)/256, 256, 0, stream>>>(X, Xb);
  transp_k <<<dim3((2*FFN_)/128, HID/64, NEXP), 256, 0, stream>>>(W1, W1t, HID, 2*FFN_);
  transp_k <<<dim3(HID/128,     FFN_/64, NEXP), 256, 0, stream>>>(W2, W2t, FFN_, HID);

  router_k <<<S_TOK,64,0, stream>>>(X, Wqkv, hdr, idx, scr);
  scan_k   <<<1,   64, 0, stream>>>(hdr);
  scatter_k<<<(S_TOK+255)/256, 256, 0, stream>>>(idx, scr, hdr, tok_slot, scr_slot);
  gemm1_k  <<<dim3(FFN_/64,  S_TOK/128, NEXP), 256, 0, stream>>>(Xb, W1t, hdr, tok_slot, inter);
  gemm2_k  <<<dim3(HID/128,  S_TOK/128, NEXP), 256, 0, stream>>>(inter, W2t, hdr, tok_slot, scr_slot, out);
}

// Round 4
// 777.401 us; speedup vs baseline: 1.0153x; 1.0153x over previous
//
#include <hip/hip_runtime.h>
#include <math.h>

#define S_TOK 2048
#define HID   2048
#define FFN_  2048
#define NEXP  8
#define CAP   2048           // per-expert slot capacity (<= S_TOK tokens per expert)

typedef short  s8v __attribute__((ext_vector_type(8)));
typedef short  s4v __attribute__((ext_vector_type(4)));
typedef float  f4v __attribute__((ext_vector_type(4)));

__device__ __forceinline__ unsigned short f32_bf16(float f){
  unsigned u = __float_as_uint(f);
  u += 0x7fffu + ((u>>16)&1u);          // RNE
  return (unsigned short)(u>>16);
}
// swizzled LDS layout: granule (r,kq) lives at position (r*4 + (kq ^ ((r>>2)&3)))
// fragment b128 reads are 2-way (free); staging writes are linear (global_load_lds).
__device__ __forceinline__ int lds_off(int r,int kq){
  return (r*4 + (kq ^ ((r>>2)&3)))*8;
}
// async global->LDS, 16B per lane; LDS dest = wave-uniform base + lane*16
__device__ __forceinline__ void gl_lds16(const unsigned short* g, unsigned short* l){
  __builtin_amdgcn_global_load_lds(
      (const __attribute__((address_space(1))) unsigned int*)(const void*)g,
      (__attribute__((address_space(3))) unsigned int*)(void*)l,
      16, 0, 0);
}

// ---------------- prep: zero out+hdr | convX | transpose W1 | transpose W2 ----------------
// grid layout (all 256-thread blocks, uniform branch per block):
//   [0,4096)        zero out (+ hdr in block 0)
//   [4096,6144)     X fp32 -> bf16
//   [6144,14336)    W1 [K=2048][N=4096] -> [N][K] bf16   (32n x 32k tiles per expert)
//   [14336,18432)   W2 [K=2048][N=2048] -> [N][K] bf16   (16n x 32k tiles per expert)
__global__ __launch_bounds__(256) void prep_k(
    const float* __restrict__ X,  unsigned short* __restrict__ Xb,
    const float* __restrict__ W1, unsigned short* __restrict__ W1t,
    const float* __restrict__ W2, unsigned short* __restrict__ W2t,
    float* __restrict__ out, int* __restrict__ hdr)
{
  const int bid = blockIdx.x, tid = threadIdx.x;
  __shared__ __align__(16) unsigned short t[128*66];

  if (bid < 4096){
    if (bid==0 && tid<8) hdr[tid] = 0;
    int i = (bid*256 + tid)*4;
    f4v z = {0.f,0.f,0.f,0.f};
    *reinterpret_cast<f4v*>(out + i) = z;
    return;
  }
  if (bid < 6144){
    int i = ((bid-4096)*256 + tid)*8;
    f4v a = *reinterpret_cast<const f4v*>(X + i);
    f4v b = *reinterpret_cast<const f4v*>(X + i + 4);
    s8v o;
    o[0]=(short)f32_bf16(a[0]); o[1]=(short)f32_bf16(a[1]);
    o[2]=(short)f32_bf16(a[2]); o[3]=(short)f32_bf16(a[3]);
    o[4]=(short)f32_bf16(b[0]); o[5]=(short)f32_bf16(b[1]);
    o[6]=(short)f32_bf16(b[2]); o[7]=(short)f32_bf16(b[3]);
    *reinterpret_cast<s8v*>(Xb + i) = o;
    return;
  }
  const float* src; unsigned short* dst; int K,N,n0,k0,e;
  if (bid < 14336){
    int b = bid - 6144; e = b>>10; int rem = b&1023;
    N = 4096; K = 2048; n0 = (rem&31)*128; k0 = (rem>>5)*64;
    src = W1; dst = W1t;
  } else {
    int b = bid - 14336; e = b>>9; int rem = b&511;
    N = 2048; K = 2048; n0 = (rem&15)*128; k0 = (rem>>4)*64;
    src = W2; dst = W2t;
  }
  src += (size_t)e*K*N + (size_t)k0*N + n0;
  dst += (size_t)e*N*K + (size_t)n0*K + k0;
  const int nb = tid & 31;        // n-chunk of 4 floats
  const int kb = tid >> 5;        // k-granule of 8 rows
  f4v f[8];
  #pragma unroll
  for (int j=0;j<8;j++)
    f[j] = *reinterpret_cast<const f4v*>(src + (size_t)(kb*8+j)*N + nb*4);
  #pragma unroll
  for (int c=0;c<4;c++){
    int n = nb*4 + c;
    s8v v;
    #pragma unroll
    for (int j=0;j<8;j++) v[j] = (short)f32_bf16(f[j][c]);
    *reinterpret_cast<s8v*>(&t[n*66 + ((kb ^ ((n>>5)&3))*8)]) = v;
  }
  __syncthreads();
  #pragma unroll
  for (int p=0;p<4;p++){
    int n = p*32 + (tid>>3);
    int c = tid & 7;
    s8v v = *reinterpret_cast<const s8v*>(&t[n*66 + ((c ^ ((n>>5)&3))*8)]);
    *reinterpret_cast<s8v*>(dst + (size_t)n*K + c*8) = v;
  }
}

// ---------------- router + scatter: one wave per token, all fp32 ----------------
__global__ __launch_bounds__(64) void router_k(
    const float* __restrict__ X, const float* __restrict__ Wqkv,
    int* __restrict__ hdr, int* __restrict__ tok_slot, float* __restrict__ scr_slot)
{
  const int s = blockIdx.x, lane = threadIdx.x;
  const float* x = X + (size_t)s*HID;
  f4v xv[8];
  #pragma unroll
  for (int i=0;i<8;i++) xv[i] = *reinterpret_cast<const f4v*>(x + (i*64+lane)*4);
  float dot[24];
  #pragma unroll
  for (int o=0;o<24;o++){
    const float* w = Wqkv + (size_t)o*HID;
    float a = 0.f;
    #pragma unroll
    for (int i=0;i<8;i++){
      f4v wv = *reinterpret_cast<const f4v*>(w + (i*64+lane)*4);
      a += xv[i][0]*wv[0] + xv[i][1]*wv[1] + xv[i][2]*wv[2] + xv[i][3]*wv[3];
    }
    #pragma unroll
    for (int off=32; off; off>>=1) a += __shfl_xor(a, off, 64);
    dot[o] = a;
  }
  if (lane==0){
    float lg[8];
    #pragma unroll
    for (int i=0;i<8;i++){
      float qi = dot[i];
      float mx = -1e30f;
      #pragma unroll
      for (int j=0;j<8;j++) mx = fmaxf(mx, qi*dot[8+j]);
      float se=0.f, lv=0.f;
      #pragma unroll
      for (int j=0;j<8;j++){
        float e = expf(qi*dot[8+j] - mx);
        se += e; lv += e*dot[16+j];
      }
      lg[i] = lv/se;
    }
    int i0=0; float v0=lg[0];
    #pragma unroll
    for (int i=1;i<8;i++) if (lg[i]>v0){v0=lg[i];i0=i;}
    int i1=-1; float v1=-1e30f;
    #pragma unroll
    for (int i=0;i<8;i++) if (i!=i0 && lg[i]>v1){v1=lg[i];i1=i;}
    float a  = expf(v1-v0);
    float s0 = 1.f/(1.f+a);
    int p0 = atomicAdd(&hdr[i0],1);
    int p1 = atomicAdd(&hdr[i1],1);
    tok_slot[i0*CAP+p0] = s;  scr_slot[i0*CAP+p0] = s0;
    tok_slot[i1*CAP+p1] = s;  scr_slot[i1*CAP+p1] = a*s0;
  }
}

// ---------------- grouped GEMM1: inter = silu(X W1g) * (X W1u) ----------------
// 1-D grid 4096 (XCD-swizzled), block 256. Tile 128 rows x (64 gate + 64 up), BK=32.
__global__ __launch_bounds__(256,3) void gemm1_k(
    const unsigned short* __restrict__ Xb, const unsigned short* __restrict__ W1t,
    const int* __restrict__ hdr, const int* __restrict__ tok_slot,
    unsigned short* __restrict__ inter)
{
  // bijective XCD swizzle: same-XCD blocks get consecutive decoded ids (mt fastest)
  const int bid = blockIdx.x;
  const int swz = (bid&7)*512 + (bid>>3);
  const int e = swz>>9, rem = swz&511, nt = rem>>4, mt = rem&15;
  const int cnt = hdr[e];
  const int m0  = mt*128;
  if (m0 >= cnt) return;
  const int off = e*CAP;
  const int n0  = nt*64;
  const unsigned short* W1e = W1t + (size_t)e*(2*FFN_)*HID;   // [n' (4096)][k (2048)]

  __shared__ __align__(16) unsigned short sA[128*32];
  __shared__ __align__(16) unsigned short sB[128*32];
  __shared__ int sTok[128];

  const int tid = threadIdx.x;
  if (tid < 128){
    int r = m0 + tid; if (r >= cnt) r = cnt-1;
    sTok[tid] = tok_slot[off + r];
  }
  __syncthreads();

  const int lane = tid & 63, wv = tid >> 6;
  const int wm = wv >> 1, wn = wv & 1;
  const int lm = lane & 15, kq = lane >> 4;
  const int srow = lane >> 2, kg = lane & 3;
  const int kgs  = kg ^ ((srow >> 2)&3);      // pre-swizzled source granule

  const unsigned short* gA0 = Xb + (size_t)sTok[wv*16 + srow]*HID      + kgs*8;
  const unsigned short* gA1 = Xb + (size_t)sTok[64 + wv*16 + srow]*HID + kgs*8;
  const unsigned short* gB0 = W1e + (size_t)(n0 + wv*16 + srow)*HID        + kgs*8; // gate
  const unsigned short* gB1 = W1e + (size_t)(FFN_ + n0 + wv*16 + srow)*HID + kgs*8; // up
  unsigned short* lA0 = sA + (wv*16)*32;
  unsigned short* lA1 = sA + (64 + wv*16)*32;
  unsigned short* lB0 = sB + (wv*16)*32;
  unsigned short* lB1 = sB + (64 + wv*16)*32;

  f4v zero = {0.f,0.f,0.f,0.f};
  f4v acc[2][2][4];
  #pragma unroll
  for (int a=0;a<2;a++)
    #pragma unroll
    for (int b=0;b<2;b++)
      #pragma unroll
      for (int c=0;c<4;c++) acc[a][b][c]=zero;

  for (int k0=0; k0<HID; k0+=32){
    gl_lds16(gA0, lA0); gl_lds16(gA1, lA1);
    gl_lds16(gB0, lB0); gl_lds16(gB1, lB1);
    gA0 += 32; gA1 += 32; gB0 += 32; gB1 += 32;
    __syncthreads();
    s8v af[4], bfr[2][2];
    #pragma unroll
    for (int mf=0;mf<4;mf++)
      af[mf] = *reinterpret_cast<const s8v*>(&sA[lds_off(wm*64+mf*16+lm, kq)]);
    #pragma unroll
    for (int st=0; st<2; st++)
      #pragma unroll
      for (int nf=0;nf<2;nf++)
        bfr[st][nf] = *reinterpret_cast<const s8v*>(&sB[lds_off(st*64+wn*32+nf*16+lm, kq)]);
    #pragma unroll
    for (int st=0; st<2; st++)
      #pragma unroll
      for (int nf=0;nf<2;nf++)
        #pragma unroll
        for (int mf=0;mf<4;mf++)
          acc[st][nf][mf] = __builtin_amdgcn_mfma_f32_16x16x32_bf16(
              af[mf], bfr[st][nf], acc[st][nf][mf], 0,0,0);
    __syncthreads();
  }
  // epilogue: silu(g)*u -> bf16 inter
  const int lq = lane>>4;
  #pragma unroll
  for (int nf=0;nf<2;nf++)
    #pragma unroll
    for (int mf=0;mf<4;mf++){
      f4v g = acc[0][nf][mf], u = acc[1][nf][mf];
      #pragma unroll
      for (int r=0;r<4;r++){
        int row = wm*64 + mf*16 + lq*4 + r;
        if (m0+row < cnt){
          float gv = g[r];
          float val = gv / (1.f + expf(-gv)) * u[r];
          inter[(size_t)(off+m0+row)*FFN_ + n0 + wn*32 + nf*16 + lm] = f32_bf16(val);
        }
      }
    }
}

// ---------------- grouped GEMM2 + combine: out[tok] += score * (inter @ W2) ----------------
// 1-D grid 2048 (XCD-swizzled), block 256. Tile 128x128, BK=32; atomic combine.
__global__ __launch_bounds__(256,3) void gemm2_k(
    const unsigned short* __restrict__ inter, const unsigned short* __restrict__ W2t,
    const int* __restrict__ hdr, const int* __restrict__ tok_slot,
    const float* __restrict__ scr_slot, float* __restrict__ out)
{
  const int bid = blockIdx.x;
  const int swz = (bid&7)*256 + (bid>>3);
  const int e = swz>>8, rem = swz&255, nt = rem>>4, mt = rem&15;
  const int cnt = hdr[e];
  const int m0  = mt*128;
  if (m0 >= cnt) return;
  const int off = e*CAP;
  const int n0  = nt*128;
  const unsigned short* W2e = W2t + (size_t)e*HID*FFN_;      // [n (2048)][k (2048)]

  __shared__ __align__(16) unsigned short sA[128*32];
  __shared__ __align__(16) unsigned short sB[128*32];
  __shared__ int   sTok[128];
  __shared__ float sScr[128];

  const int tid = threadIdx.x;
  if (tid < 128){
    int r = m0 + tid; if (r >= cnt) r = cnt-1;
    sTok[tid] = tok_slot[off + r];
    sScr[tid] = scr_slot[off + r];
  }

  const int lane = tid & 63, wv = tid >> 6;
  const int wm = wv >> 1, wn = wv & 1;
  const int lm = lane & 15, kq = lane >> 4;
  const int srow = lane >> 2, kg = lane & 3;
  const int kgs  = kg ^ ((srow >> 2)&3);

  int r0 = m0 + wv*16 + srow;      if (r0 >= cnt) r0 = cnt-1;
  int r1 = m0 + 64 + wv*16 + srow; if (r1 >= cnt) r1 = cnt-1;
  const unsigned short* gA0 = inter + (size_t)(off + r0)*FFN_ + kgs*8;
  const unsigned short* gA1 = inter + (size_t)(off + r1)*FFN_ + kgs*8;
  const unsigned short* gB0 = W2e + (size_t)(n0 + wv*16 + srow)*FFN_      + kgs*8;
  const unsigned short* gB1 = W2e + (size_t)(n0 + 64 + wv*16 + srow)*FFN_ + kgs*8;
  unsigned short* lA0 = sA + (wv*16)*32;
  unsigned short* lA1 = sA + (64 + wv*16)*32;
  unsigned short* lB0 = sB + (wv*16)*32;
  unsigned short* lB1 = sB + (64 + wv*16)*32;

  f4v zero = {0.f,0.f,0.f,0.f};
  f4v acc[4][4];
  #pragma unroll
  for (int a=0;a<4;a++)
    #pragma unroll
    for (int b=0;b<4;b++) acc[a][b]=zero;

  __syncthreads();

  for (int k0=0; k0<FFN_; k0+=32){
    gl_lds16(gA0, lA0); gl_lds16(gA1, lA1);
    gl_lds16(gB0, lB0); gl_lds16(gB1, lB1);
    gA0 += 32; gA1 += 32; gB0 += 32; gB1 += 32;
    __syncthreads();
    s8v af[4], bfr[4];
    #pragma unroll
    for (int mf=0;mf<4;mf++)
      af[mf] = *reinterpret_cast<const s8v*>(&sA[lds_off(wm*64+mf*16+lm, kq)]);
    #pragma unroll
    for (int nf=0;nf<4;nf++)
      bfr[nf] = *reinterpret_cast<const s8v*>(&sB[lds_off(wn*64+nf*16+lm, kq)]);
    #pragma unroll
    for (int nf=0;nf<4;nf++)
      #pragma unroll
      for (int mf=0;mf<4;mf++)
        acc[nf][mf] = __builtin_amdgcn_mfma_f32_16x16x32_bf16(
            af[mf], bfr[nf], acc[nf][mf], 0,0,0);
    __syncthreads();
  }
  const int lq = lane>>4;
  #pragma unroll
  for (int nf=0;nf<4;nf++)
    #pragma unroll
    for (int mf=0;mf<4;mf++)
      #pragma unroll
      for (int r=0;r<4;r++){
        int row = wm*64 + mf*16 + lq*4 + r;
        if (m0+row < cnt)
          atomicAdd(&out[(size_t)sTok[row]*HID + n0 + wn*64 + nf*16 + lm],
                    acc[nf][mf][r]*sScr[row]);
      }
}

extern "C" void kernel_launch(void* const* d_in, const int* in_sizes, int n_in,
                              void* d_out, int out_size, void* d_ws, size_t ws_size,
                              hipStream_t stream)
{
  const float* X    = (const float*)d_in[0];
  const float* Wqkv = (const float*)d_in[1];
  const float* W1   = (const float*)d_in[2];
  const float* W2   = (const float*)d_in[3];
  float* out = (float*)d_out;

  // workspace layout (~277 MB)
  char* ws = (char*)d_ws;
  int*   hdr      = (int*)ws;                              // counts[8]
  int*   tok_slot = (int*)(ws + 4096);                     // NEXP*CAP ints   (64 KB)
  float* scr_slot = (float*)(ws + 4096 + 65536);           // NEXP*CAP floats (64 KB)
  size_t o = 4096 + 2*65536;                               // 135168
  unsigned short* Xb    = (unsigned short*)(ws + o); o += (size_t)S_TOK*HID*2;       // 8 MB
  unsigned short* inter = (unsigned short*)(ws + o); o += (size_t)NEXP*CAP*FFN_*2;   // 64 MB
  unsigned short* W1t   = (unsigned short*)(ws + o); o += (size_t)NEXP*2*FFN_*HID*2; // 128 MB
  unsigned short* W2t   = (unsigned short*)(ws + o);                                 // 64 MB

  prep_k   <<<18432, 256, 0, stream>>>(X, Xb, W1, W1t, W2, W2t, out, hdr);
  router_k <<<S_TOK, 64,  0, stream>>>(X, Wqkv, hdr, tok_slot, scr_slot);
  gemm1_k  <<<4096,  256, 0, stream>>>(Xb, W1t, hdr, tok_slot, inter);
  gemm2_k  <<<2048,  256, 0, stream>>>(inter, W2t, hdr, tok_slot, scr_slot, out);
}

// Round 5
// 777.291 us; speedup vs baseline: 1.0155x; 1.0001x over previous
//
#include <hip/hip_runtime.h>
#include <math.h>

#define S_TOK 2048
#define HID   2048
#define FFN_  2048
#define NEXP  8
#define CAP   2048           // per-expert slot capacity (<= S_TOK tokens per expert)

typedef short  s8v __attribute__((ext_vector_type(8)));
typedef short  s4v __attribute__((ext_vector_type(4)));
typedef float  f4v __attribute__((ext_vector_type(4)));

__device__ __forceinline__ unsigned short f32_bf16(float f){
  unsigned u = __float_as_uint(f);
  u += 0x7fffu + ((u>>16)&1u);          // RNE
  return (unsigned short)(u>>16);
}
// swizzled LDS layout for GEMM tiles: granule (r,kq) at (r*4 + (kq ^ ((r>>2)&3)))
__device__ __forceinline__ int lds_off(int r,int kq){
  return (r*4 + (kq ^ ((r>>2)&3)))*8;
}
// async global->LDS, 16B per lane; LDS dest = wave-uniform base + lane*16
__device__ __forceinline__ void gl_lds16(const unsigned short* g, unsigned short* l){
  __builtin_amdgcn_global_load_lds(
      (const __attribute__((address_space(1))) unsigned int*)(const void*)g,
      (__attribute__((address_space(3))) unsigned int*)(void*)l,
      16, 0, 0);
}

// ---------------- prep: router | transpose W1 | transpose W2 | zero out | convX ----------------
// grid (256-thread blocks, uniform branch per block):
//   [0,512)        router: 4 tokens/block (1 per wave)
//   [512,4608)     W1 [K=2048][N=4096] -> [N][K] bf16, tiles 256k x 64n
//   [4608,6656)    W2 [K=2048][N=2048] -> [N][K] bf16, tiles 256k x 64n
//   [6656,7680)    zero out (gemm2 accumulates atomically)
//   [7680,8704)    X fp32 -> bf16
__global__ __launch_bounds__(256) void prep_k(
    const float* __restrict__ X,  unsigned short* __restrict__ Xb,
    const float* __restrict__ W1, unsigned short* __restrict__ W1t,
    const float* __restrict__ W2, unsigned short* __restrict__ W2t,
    const float* __restrict__ Wqkv,
    float* __restrict__ out, int* __restrict__ hdr,
    int* __restrict__ tok_slot, float* __restrict__ scr_slot)
{
  const int bid = blockIdx.x, tid = threadIdx.x;
  __shared__ __align__(16) unsigned short t[64*264];   // 33 KB transpose tile

  if (bid < 512){
    // ---------------- router: one wave per token, all fp32 ----------------
    const int lane = tid & 63;
    const int s = bid*4 + (tid >> 6);
    const float* x = X + (size_t)s*HID;
    f4v xv[8];
    #pragma unroll
    for (int i=0;i<8;i++) xv[i] = *reinterpret_cast<const f4v*>(x + (i*64+lane)*4);
    float dot[24];
    #pragma unroll
    for (int o=0;o<24;o++){
      const float* w = Wqkv + (size_t)o*HID;
      float a = 0.f;
      #pragma unroll
      for (int i=0;i<8;i++){
        f4v wv = *reinterpret_cast<const f4v*>(w + (i*64+lane)*4);
        a += xv[i][0]*wv[0] + xv[i][1]*wv[1] + xv[i][2]*wv[2] + xv[i][3]*wv[3];
      }
      #pragma unroll
      for (int off=32; off; off>>=1) a += __shfl_xor(a, off, 64);
      dot[o] = a;
    }
    if (lane==0){
      float lg[8];
      #pragma unroll
      for (int i=0;i<8;i++){
        float qi = dot[i];
        float mx = -1e30f;
        #pragma unroll
        for (int j=0;j<8;j++) mx = fmaxf(mx, qi*dot[8+j]);
        float se=0.f, lv=0.f;
        #pragma unroll
        for (int j=0;j<8;j++){
          float e = expf(qi*dot[8+j] - mx);
          se += e; lv += e*dot[16+j];
        }
        lg[i] = lv/se;
      }
      int i0=0; float v0=lg[0];
      #pragma unroll
      for (int i=1;i<8;i++) if (lg[i]>v0){v0=lg[i];i0=i;}
      int i1=-1; float v1=-1e30f;
      #pragma unroll
      for (int i=0;i<8;i++) if (i!=i0 && lg[i]>v1){v1=lg[i];i1=i;}
      float a  = expf(v1-v0);
      float s0 = 1.f/(1.f+a);
      int p0 = atomicAdd(&hdr[i0],1);
      int p1 = atomicAdd(&hdr[i1],1);
      tok_slot[i0*CAP+p0] = s;  scr_slot[i0*CAP+p0] = s0;
      tok_slot[i1*CAP+p1] = s;  scr_slot[i1*CAP+p1] = a*s0;
    }
    return;
  }
  if (bid < 6656){
    // ---------------- weight transpose, tile 256k x 64n ----------------
    const float* src; unsigned short* dst; int N, n0, k0;
    if (bid < 4608){
      int b = bid - 512; int e = b>>9; int rem = b&511;
      N = 4096; n0 = (rem&63)*64; k0 = (rem>>6)*256;
      src = W1 + (size_t)e*2048*4096; dst = W1t + (size_t)e*4096*2048;
    } else {
      int b = bid - 4608; int e = b>>8; int rem = b&255;
      N = 2048; n0 = (rem&31)*64; k0 = (rem>>5)*256;
      src = W2 + (size_t)e*2048*2048; dst = W2t + (size_t)e*2048*2048;
    }
    src += (size_t)k0*N + n0;
    dst += (size_t)n0*2048 + k0;           // K == 2048 for both
    const int nb = tid & 15;               // n-chunk of 4
    const int kb = tid >> 4;               // 16 k-rows: kb*16 .. +15
    s8v col[4][2];                         // [c][half]: 16 bf16 per column
    #pragma unroll
    for (int j=0;j<16;j++){
      f4v f = *reinterpret_cast<const f4v*>(src + (size_t)(kb*16+j)*N + nb*4);
      #pragma unroll
      for (int c=0;c<4;c++)
        ((unsigned short*)&col[c][j>>3])[j&7] = f32_bf16(f[c]);
    }
    #pragma unroll
    for (int c=0;c<4;c++){
      int n = nb*4 + c;
      #pragma unroll
      for (int h=0;h<2;h++){
        int g  = kb*2 + h;
        int gs = g ^ (nb & 7);             // nb == n>>2 ; XOR bank-spread
        *reinterpret_cast<s8v*>(&t[n*264 + gs*8]) = col[c][h];
      }
    }
    __syncthreads();
    #pragma unroll
    for (int p=0;p<8;p++){
      int idx = p*256 + tid;               // 0..2047
      int n = idx >> 5, g = idx & 31;
      int gs = g ^ ((n>>2) & 7);
      s8v v = *reinterpret_cast<const s8v*>(&t[n*264 + gs*8]);
      *reinterpret_cast<s8v*>(dst + (size_t)n*2048 + g*8) = v;  // 512B/row contiguous
    }
    return;
  }
  if (bid < 7680){
    // ---------------- zero out ----------------
    int i = ((bid-6656)*256 + tid)*16;
    f4v z = {0.f,0.f,0.f,0.f};
    *reinterpret_cast<f4v*>(out + i)      = z;
    *reinterpret_cast<f4v*>(out + i + 4)  = z;
    *reinterpret_cast<f4v*>(out + i + 8)  = z;
    *reinterpret_cast<f4v*>(out + i + 12) = z;
    return;
  }
  {
    // ---------------- X fp32 -> bf16 ----------------
    int i = ((bid-7680)*256 + tid)*16;
    f4v a = *reinterpret_cast<const f4v*>(X + i);
    f4v b = *reinterpret_cast<const f4v*>(X + i + 4);
    f4v c = *reinterpret_cast<const f4v*>(X + i + 8);
    f4v d = *reinterpret_cast<const f4v*>(X + i + 12);
    s8v o0, o1;
    o0[0]=(short)f32_bf16(a[0]); o0[1]=(short)f32_bf16(a[1]);
    o0[2]=(short)f32_bf16(a[2]); o0[3]=(short)f32_bf16(a[3]);
    o0[4]=(short)f32_bf16(b[0]); o0[5]=(short)f32_bf16(b[1]);
    o0[6]=(short)f32_bf16(b[2]); o0[7]=(short)f32_bf16(b[3]);
    o1[0]=(short)f32_bf16(c[0]); o1[1]=(short)f32_bf16(c[1]);
    o1[2]=(short)f32_bf16(c[2]); o1[3]=(short)f32_bf16(c[3]);
    o1[4]=(short)f32_bf16(d[0]); o1[5]=(short)f32_bf16(d[1]);
    o1[6]=(short)f32_bf16(d[2]); o1[7]=(short)f32_bf16(d[3]);
    *reinterpret_cast<s8v*>(Xb + i)     = o0;
    *reinterpret_cast<s8v*>(Xb + i + 8) = o1;
  }
}

// ---------------- grouped GEMM1: inter = silu(X W1g) * (X W1u) ----------------
// 1-D grid 4096 (XCD-swizzled), block 256. Tile 128 rows x (64 gate + 64 up), BK=32.
__global__ __launch_bounds__(256,3) void gemm1_k(
    const unsigned short* __restrict__ Xb, const unsigned short* __restrict__ W1t,
    const int* __restrict__ hdr, const int* __restrict__ tok_slot,
    unsigned short* __restrict__ inter)
{
  // bijective XCD swizzle: same-XCD blocks get consecutive decoded ids (mt fastest)
  const int bid = blockIdx.x;
  const int swz = (bid&7)*512 + (bid>>3);
  const int e = swz>>9, rem = swz&511, nt = rem>>4, mt = rem&15;
  const int cnt = hdr[e];
  const int m0  = mt*128;
  if (m0 >= cnt) return;
  const int off = e*CAP;
  const int n0  = nt*64;
  const unsigned short* W1e = W1t + (size_t)e*(2*FFN_)*HID;   // [n' (4096)][k (2048)]

  __shared__ __align__(16) unsigned short sA[128*32];
  __shared__ __align__(16) unsigned short sB[128*32];
  __shared__ int sTok[128];

  const int tid = threadIdx.x;
  if (tid < 128){
    int r = m0 + tid; if (r >= cnt) r = cnt-1;
    sTok[tid] = tok_slot[off + r];
  }
  __syncthreads();

  const int lane = tid & 63, wv = tid >> 6;
  const int wm = wv >> 1, wn = wv & 1;
  const int lm = lane & 15, kq = lane >> 4;
  const int srow = lane >> 2, kg = lane & 3;
  const int kgs  = kg ^ ((srow >> 2)&3);      // pre-swizzled source granule

  const unsigned short* gA0 = Xb + (size_t)sTok[wv*16 + srow]*HID      + kgs*8;
  const unsigned short* gA1 = Xb + (size_t)sTok[64 + wv*16 + srow]*HID + kgs*8;
  const unsigned short* gB0 = W1e + (size_t)(n0 + wv*16 + srow)*HID        + kgs*8; // gate
  const unsigned short* gB1 = W1e + (size_t)(FFN_ + n0 + wv*16 + srow)*HID + kgs*8; // up
  unsigned short* lA0 = sA + (wv*16)*32;
  unsigned short* lA1 = sA + (64 + wv*16)*32;
  unsigned short* lB0 = sB + (wv*16)*32;
  unsigned short* lB1 = sB + (64 + wv*16)*32;

  f4v zero = {0.f,0.f,0.f,0.f};
  f4v acc[2][2][4];
  #pragma unroll
  for (int a=0;a<2;a++)
    #pragma unroll
    for (int b=0;b<2;b++)
      #pragma unroll
      for (int c=0;c<4;c++) acc[a][b][c]=zero;

  for (int k0=0; k0<HID; k0+=32){
    gl_lds16(gA0, lA0); gl_lds16(gA1, lA1);
    gl_lds16(gB0, lB0); gl_lds16(gB1, lB1);
    gA0 += 32; gA1 += 32; gB0 += 32; gB1 += 32;
    __syncthreads();
    s8v af[4], bfr[2][2];
    #pragma unroll
    for (int mf=0;mf<4;mf++)
      af[mf] = *reinterpret_cast<const s8v*>(&sA[lds_off(wm*64+mf*16+lm, kq)]);
    #pragma unroll
    for (int st=0; st<2; st++)
      #pragma unroll
      for (int nf=0;nf<2;nf++)
        bfr[st][nf] = *reinterpret_cast<const s8v*>(&sB[lds_off(st*64+wn*32+nf*16+lm, kq)]);
    #pragma unroll
    for (int st=0; st<2; st++)
      #pragma unroll
      for (int nf=0;nf<2;nf++)
        #pragma unroll
        for (int mf=0;mf<4;mf++)
          acc[st][nf][mf] = __builtin_amdgcn_mfma_f32_16x16x32_bf16(
              af[mf], bfr[st][nf], acc[st][nf][mf], 0,0,0);
    __syncthreads();
  }
  // epilogue: silu(g)*u -> bf16 inter
  const int lq = lane>>4;
  #pragma unroll
  for (int nf=0;nf<2;nf++)
    #pragma unroll
    for (int mf=0;mf<4;mf++){
      f4v g = acc[0][nf][mf], u = acc[1][nf][mf];
      #pragma unroll
      for (int r=0;r<4;r++){
        int row = wm*64 + mf*16 + lq*4 + r;
        if (m0+row < cnt){
          float gv = g[r];
          float val = gv / (1.f + expf(-gv)) * u[r];
          inter[(size_t)(off+m0+row)*FFN_ + n0 + wn*32 + nf*16 + lm] = f32_bf16(val);
        }
      }
    }
}

// ---------------- grouped GEMM2 + combine: out[tok] += score * (inter @ W2) ----------------
// 1-D grid 2048 (XCD-swizzled), block 256. Tile 128x128, BK=32; atomic combine.
__global__ __launch_bounds__(256,3) void gemm2_k(
    const unsigned short* __restrict__ inter, const unsigned short* __restrict__ W2t,
    const int* __restrict__ hdr, const int* __restrict__ tok_slot,
    const float* __restrict__ scr_slot, float* __restrict__ out)
{
  const int bid = blockIdx.x;
  const int swz = (bid&7)*256 + (bid>>3);
  const int e = swz>>8, rem = swz&255, nt = rem>>4, mt = rem&15;
  const int cnt = hdr[e];
  const int m0  = mt*128;
  if (m0 >= cnt) return;
  const int off = e*CAP;
  const int n0  = nt*128;
  const unsigned short* W2e = W2t + (size_t)e*HID*FFN_;      // [n (2048)][k (2048)]

  __shared__ __align__(16) unsigned short sA[128*32];
  __shared__ __align__(16) unsigned short sB[128*32];
  __shared__ int   sTok[128];
  __shared__ float sScr[128];

  const int tid = threadIdx.x;
  if (tid < 128){
    int r = m0 + tid; if (r >= cnt) r = cnt-1;
    sTok[tid] = tok_slot[off + r];
    sScr[tid] = scr_slot[off + r];
  }

  const int lane = tid & 63, wv = tid >> 6;
  const int wm = wv >> 1, wn = wv & 1;
  const int lm = lane & 15, kq = lane >> 4;
  const int srow = lane >> 2, kg = lane & 3;
  const int kgs  = kg ^ ((srow >> 2)&3);

  int r0 = m0 + wv*16 + srow;      if (r0 >= cnt) r0 = cnt-1;
  int r1 = m0 + 64 + wv*16 + srow; if (r1 >= cnt) r1 = cnt-1;
  const unsigned short* gA0 = inter + (size_t)(off + r0)*FFN_ + kgs*8;
  const unsigned short* gA1 = inter + (size_t)(off + r1)*FFN_ + kgs*8;
  const unsigned short* gB0 = W2e + (size_t)(n0 + wv*16 + srow)*FFN_      + kgs*8;
  const unsigned short* gB1 = W2e + (size_t)(n0 + 64 + wv*16 + srow)*FFN_ + kgs*8;
  unsigned short* lA0 = sA + (wv*16)*32;
  unsigned short* lA1 = sA + (64 + wv*16)*32;
  unsigned short* lB0 = sB + (wv*16)*32;
  unsigned short* lB1 = sB + (64 + wv*16)*32;

  f4v zero = {0.f,0.f,0.f,0.f};
  f4v acc[4][4];
  #pragma unroll
  for (int a=0;a<4;a++)
    #pragma unroll
    for (int b=0;b<4;b++) acc[a][b]=zero;

  __syncthreads();

  for (int k0=0; k0<FFN_; k0+=32){
    gl_lds16(gA0, lA0); gl_lds16(gA1, lA1);
    gl_lds16(gB0, lB0); gl_lds16(gB1, lB1);
    gA0 += 32; gA1 += 32; gB0 += 32; gB1 += 32;
    __syncthreads();
    s8v af[4], bfr[4];
    #pragma unroll
    for (int mf=0;mf<4;mf++)
      af[mf] = *reinterpret_cast<const s8v*>(&sA[lds_off(wm*64+mf*16+lm, kq)]);
    #pragma unroll
    for (int nf=0;nf<4;nf++)
      bfr[nf] = *reinterpret_cast<const s8v*>(&sB[lds_off(wn*64+nf*16+lm, kq)]);
    #pragma unroll
    for (int nf=0;nf<4;nf++)
      #pragma unroll
      for (int mf=0;mf<4;mf++)
        acc[nf][mf] = __builtin_amdgcn_mfma_f32_16x16x32_bf16(
            af[mf], bfr[nf], acc[nf][mf], 0,0,0);
    __syncthreads();
  }
  const int lq = lane>>4;
  #pragma unroll
  for (int nf=0;nf<4;nf++)
    #pragma unroll
    for (int mf=0;mf<4;mf++)
      #pragma unroll
      for (int r=0;r<4;r++){
        int row = wm*64 + mf*16 + lq*4 + r;
        if (m0+row < cnt)
          atomicAdd(&out[(size_t)sTok[row]*HID + n0 + wn*64 + nf*16 + lm],
                    acc[nf][mf][r]*sScr[row]);
      }
}

extern "C" void kernel_launch(void* const* d_in, const int* in_sizes, int n_in,
                              void* d_out, int out_size, void* d_ws, size_t ws_size,
                              hipStream_t stream)
{
  const float* X    = (const float*)d_in[0];
  const float* Wqkv = (const float*)d_in[1];
  const float* W1   = (const float*)d_in[2];
  const float* W2   = (const float*)d_in[3];
  float* out = (float*)d_out;

  // workspace layout (~277 MB)
  char* ws = (char*)d_ws;
  int*   hdr      = (int*)ws;                              // counts[8]
  int*   tok_slot = (int*)(ws + 4096);                     // NEXP*CAP ints   (64 KB)
  float* scr_slot = (float*)(ws + 4096 + 65536);           // NEXP*CAP floats (64 KB)
  size_t o = 4096 + 2*65536;                               // 135168
  unsigned short* Xb    = (unsigned short*)(ws + o); o += (size_t)S_TOK*HID*2;       // 8 MB
  unsigned short* inter = (unsigned short*)(ws + o); o += (size_t)NEXP*CAP*FFN_*2;   // 64 MB
  unsigned short* W1t   = (unsigned short*)(ws + o); o += (size_t)NEXP*2*FFN_*HID*2; // 128 MB
  unsigned short* W2t   = (unsigned short*)(ws + o);                                 // 64 MB

  hipMemsetAsync(hdr, 0, 32, stream);
  prep_k   <<<8704,  256, 0, stream>>>(X, Xb, W1, W1t, W2, W2t, Wqkv, out, hdr,
                                       tok_slot, scr_slot);
  gemm1_k  <<<4096,  256, 0, stream>>>(Xb, W1t, hdr, tok_slot, inter);
  gemm2_k  <<<2048,  256, 0, stream>>>(inter, W2t, hdr, tok_slot, scr_slot, out);
}